// Round 1
// baseline (69.852 us; speedup 1.0000x reference)
//
#include <hip/hip_runtime.h>
#include <hip/hip_bf16.h>
#include <math.h>

#define NB 128
#define ND 1024
#define NO 512
#define NK3 1536
#define EPSV 1e-5f
#define SCALEQK 0.04419417382415922f   // 1/sqrt(512)
#define LOG2E 1.4426950408889634f

// ws layout (floats):
//   Tpart : [NB*4]                       @ 0
//   pA    : [4 gemms][8 ksplit][NB][NO]  @ 512
//   feat  : [NB][NK3]                    @ 512 + 4*8*NB*NO
//   pB    : [12 ksplit][NB][NO]          @ ... (total ~11.8 MB)
#define WS_TPART 0
#define WS_PA    512
#define WS_FEAT  (WS_PA + 4*8*NB*NO)
#define WS_PB    (WS_FEAT + NB*NK3)

static __device__ __forceinline__ float fast_exp2(float v) {
#if __has_builtin(__builtin_amdgcn_exp2f)
  return __builtin_amdgcn_exp2f(v);
#else
  return exp2f(v);
#endif
}

// -------- attention cell reduced to T_b = sum_d ek_d * t[b,d] --------
// grid (4 d-chunks, 128 b), 256 threads
__global__ __launch_bounds__(256) void attn_kernel(
    const float* __restrict__ x, const float* __restrict__ embk,
    const float* __restrict__ embb, const float* __restrict__ ekd,
    float* __restrict__ Tpart) {
  __shared__ float xsh[ND];
  __shared__ float red[4][4];
  __shared__ float bc[4];
  const int t = threadIdx.x;
  const int ch = blockIdx.x;
  const int b = blockIdx.y;

  *(float4*)&xsh[t * 4] = *(const float4*)&x[b * ND + t * 4];

  // S1 = sum_o qk*kk ; S3 = sum_o kk*qb
  float s1, s3;
  {
    float kk = embk[NO + t];
    s1 = embk[t] * kk;
    s3 = kk * embb[t];
    int o = t + 256;
    float kk2 = embk[NO + o];
    s1 = fmaf(embk[o], kk2, s1);
    s3 = fmaf(kk2, embb[o], s3);
  }
  __syncthreads();
  float xmx = xsh[t * 4], xmn = xmx;
#pragma unroll
  for (int j = 1; j < 4; ++j) {
    float v = xsh[t * 4 + j];
    xmx = fmaxf(xmx, v);
    xmn = fminf(xmn, v);
  }
#pragma unroll
  for (int off = 32; off; off >>= 1) {
    s1 += __shfl_xor(s1, off);
    s3 += __shfl_xor(s3, off);
    xmx = fmaxf(xmx, __shfl_xor(xmx, off));
    xmn = fminf(xmn, __shfl_xor(xmn, off));
  }
  const int w = t >> 6;
  if ((t & 63) == 0) { red[0][w] = s1; red[1][w] = s3; red[2][w] = xmx; red[3][w] = xmn; }
  __syncthreads();
  if (t == 0) {
    bc[0] = red[0][0] + red[0][1] + red[0][2] + red[0][3];
    bc[1] = red[1][0] + red[1][1] + red[1][2] + red[1][3];
    bc[2] = fmaxf(fmaxf(red[2][0], red[2][1]), fmaxf(red[2][2], red[2][3]));
    bc[3] = fminf(fminf(red[3][0], red[3][1]), fminf(red[3][2], red[3][3]));
  }
  __syncthreads();
  const float S1 = bc[0], S3 = bc[1];
  const float gxmx = bc[2], gxmn = bc[3];

  const int d = ch * 256 + t;
  // softmax_e( c * x_e ), c = scale*(x_bd*S1 + S3); work in log2 domain
  const float c2 = SCALEQK * LOG2E * fmaf(xsh[d], S1, S3);
  const float mx2 = (c2 >= 0.f) ? c2 * gxmx : c2 * gxmn;
  float s0a = 0.f, s0b = 0.f, sxa = 0.f, sxb = 0.f;
#pragma unroll 2
  for (int e4 = 0; e4 < ND / 4; ++e4) {
    const float4 xe = *(const float4*)&xsh[e4 * 4];
    const float p0 = fast_exp2(fmaf(c2, xe.x, -mx2));
    const float p1 = fast_exp2(fmaf(c2, xe.y, -mx2));
    const float p2 = fast_exp2(fmaf(c2, xe.z, -mx2));
    const float p3 = fast_exp2(fmaf(c2, xe.w, -mx2));
    s0a += p0; sxa = fmaf(p0, xe.x, sxa);
    s0b += p1; sxb = fmaf(p1, xe.y, sxb);
    s0a += p2; sxa = fmaf(p2, xe.z, sxa);
    s0b += p3; sxb = fmaf(p3, xe.w, sxb);
  }
  const float td = (sxa + sxb) / (s0a + s0b);
  float contrib = ekd[d] * td;
#pragma unroll
  for (int off = 32; off; off >>= 1) contrib += __shfl_xor(contrib, off);
  __syncthreads();
  if ((t & 63) == 0) red[0][w] = contrib;
  __syncthreads();
  if (t == 0) Tpart[b * 4 + ch] = red[0][0] + red[0][1] + red[0][2] + red[0][3];
}

// -------- 4 fused-family GEMMs: g0: x@k1, g1: x@gt, g2: x@wa, g3: asinh(x)@wa --------
// grid (8 o-tiles, 2 b-tiles, 4 g * 8 ksplit), 256 threads; tiles 64b x 64o, kchunk 128
__global__ __launch_bounds__(256) void gemmA_kernel(
    const float* __restrict__ x, const float* __restrict__ gt,
    const float* __restrict__ wt, const float* __restrict__ mt,
    const float* __restrict__ k1, float* __restrict__ pA) {
  __shared__ float As[64][129];
  __shared__ float Ws[128][64];
  const int t = threadIdx.x;
  const int o0 = blockIdx.x * 64, b0 = blockIdx.y * 64;
  const int g = blockIdx.z >> 3, ks = blockIdx.z & 7;
  const int k0 = ks * 128;
  {
    const int ci = t & 31, r0 = t >> 5;
#pragma unroll
    for (int pass = 0; pass < 8; ++pass) {
      const int r = pass * 8 + r0;
      float4 v = *(const float4*)&x[(size_t)(b0 + r) * ND + k0 + ci * 4];
      if (g == 3) { v.x = asinhf(v.x); v.y = asinhf(v.y); v.z = asinhf(v.z); v.w = asinhf(v.w); }
      As[r][ci * 4 + 0] = v.x; As[r][ci * 4 + 1] = v.y;
      As[r][ci * 4 + 2] = v.z; As[r][ci * 4 + 3] = v.w;
    }
  }
  {
    const int ci = t & 15, r0 = t >> 4;
#pragma unroll
    for (int pass = 0; pass < 8; ++pass) {
      const int r = pass * 16 + r0;
      const size_t idx = (size_t)(k0 + r) * NO + o0 + ci * 4;
      float4 wv;
      if (g == 0) wv = *(const float4*)&k1[idx];
      else if (g == 1) wv = *(const float4*)&gt[idx];
      else {
        const float4 a = *(const float4*)&wt[idx];
        const float4 m = *(const float4*)&mt[idx];
        wv.x = tanhf(a.x) * (1.f / (1.f + __expf(-m.x)));
        wv.y = tanhf(a.y) * (1.f / (1.f + __expf(-m.y)));
        wv.z = tanhf(a.z) * (1.f / (1.f + __expf(-m.z)));
        wv.w = tanhf(a.w) * (1.f / (1.f + __expf(-m.w)));
      }
      *(float4*)&Ws[r][ci * 4] = wv;
    }
  }
  __syncthreads();
  const int tx = t & 15, ty = t >> 4;
  float acc[4][4] = {};
#pragma unroll 2
  for (int k = 0; k < 128; ++k) {
    const float4 wv = *(const float4*)&Ws[k][tx * 4];
#pragma unroll
    for (int i = 0; i < 4; ++i) {
      const float av = As[ty * 4 + i][k];
      acc[i][0] = fmaf(av, wv.x, acc[i][0]);
      acc[i][1] = fmaf(av, wv.y, acc[i][1]);
      acc[i][2] = fmaf(av, wv.z, acc[i][2]);
      acc[i][3] = fmaf(av, wv.w, acc[i][3]);
    }
  }
  float* base = pA + ((size_t)(g * 8 + ks) * NB + b0) * NO + o0;
#pragma unroll
  for (int i = 0; i < 4; ++i)
    *(float4*)&base[(ty * 4 + i) * NO + tx * 4] =
        make_float4(acc[i][0], acc[i][1], acc[i][2], acc[i][3]);
}

// -------- combine: nonlinearities + c4 layernorm -> feat [NB][NK3] --------
__global__ __launch_bounds__(256) void combineA_kernel(
    const float* __restrict__ pA, const float* __restrict__ Tpart,
    const float* __restrict__ bias1, const float* __restrict__ embk,
    const float* __restrict__ embb, const float* __restrict__ ekd,
    const float* __restrict__ ng, const float* __restrict__ nb,
    float* __restrict__ feat) {
  __shared__ float red[6][4];
  __shared__ float bc[6];
  const int t = threadIdx.x;
  const int p = blockIdx.x * 256 + t;
  const int b = p >> 9, o = p & 511;

  float svk = 0, svb = 0, svk2 = 0, svkvb = 0, svb2 = 0, se = 0;
#pragma unroll
  for (int j = 0; j < 2; ++j) {
    const int oo = t + j * 256;
    const float vk = embk[2 * NO + oo], vb = embb[2 * NO + oo];
    svk += vk; svb += vb;
    svk2 = fmaf(vk, vk, svk2);
    svkvb = fmaf(vk, vb, svkvb);
    svb2 = fmaf(vb, vb, svb2);
  }
#pragma unroll
  for (int j = 0; j < 4; ++j) se += ekd[t + j * 256];
#pragma unroll
  for (int off = 32; off; off >>= 1) {
    svk += __shfl_xor(svk, off); svb += __shfl_xor(svb, off);
    svk2 += __shfl_xor(svk2, off); svkvb += __shfl_xor(svkvb, off);
    svb2 += __shfl_xor(svb2, off); se += __shfl_xor(se, off);
  }
  const int w = t >> 6;
  if ((t & 63) == 0) {
    red[0][w] = svk; red[1][w] = svb; red[2][w] = svk2;
    red[3][w] = svkvb; red[4][w] = svb2; red[5][w] = se;
  }
  __syncthreads();
  if (t < 6) bc[t] = red[t][0] + red[t][1] + red[t][2] + red[t][3];
  __syncthreads();
  const float inv_o = 1.f / (float)NO;
  const float mvk = bc[0] * inv_o, mvb = bc[1] * inv_o;
  const float Mvk2 = bc[2] * inv_o - mvk * mvk;
  const float Mvkvb = bc[3] * inv_o - mvk * mvb;
  const float Mvb2 = bc[4] * inv_o - mvb * mvb;
  const float E = bc[5];

  float d1 = 0, d2 = 0, d3 = 0, d4 = 0;
#pragma unroll
  for (int ks = 0; ks < 8; ++ks) {
    d1 += pA[((size_t)(0 * 8 + ks) * NB + b) * NO + o];
    d2 += pA[((size_t)(1 * 8 + ks) * NB + b) * NO + o];
    d3 += pA[((size_t)(2 * 8 + ks) * NB + b) * NO + o];
    d4 += pA[((size_t)(3 * 8 + ks) * NB + b) * NO + o];
  }
  const float c1v = d1 + bias1[o];
  const float gg = 1.f / (1.f + __expf(-d2));
  const float mm = sinhf(d4);
  const float c3v = fmaf(gg, d3 - mm, mm);
  const float T = Tpart[b * 4] + Tpart[b * 4 + 1] + Tpart[b * 4 + 2] + Tpart[b * 4 + 3];
  const float vkc = embk[2 * NO + o] - mvk, vbc = embb[2 * NO + o] - mvb;
  const float var = T * T * Mvk2 + 2.f * T * E * Mvkvb + E * E * Mvb2;
  const float c4v = (T * vkc + E * vbc) * rsqrtf(var + EPSV) * ng[o] + nb[o];
  float* fb = feat + (size_t)b * NK3;
  fb[o] = c1v;
  fb[NO + o] = c3v;
  fb[2 * NO + o] = c4v;
}

// -------- final GEMM: feat[128,1536] @ k3[1536,512] --------
// grid (8 o-tiles, 2 b-tiles, 12 ksplit)
__global__ __launch_bounds__(256) void gemmB_kernel(
    const float* __restrict__ feat, const float* __restrict__ k3,
    float* __restrict__ pB) {
  __shared__ float As[64][129];
  __shared__ float Ws[128][64];
  const int t = threadIdx.x;
  const int o0 = blockIdx.x * 64, b0 = blockIdx.y * 64, k0 = blockIdx.z * 128;
  {
    const int ci = t & 31, r0 = t >> 5;
#pragma unroll
    for (int pass = 0; pass < 8; ++pass) {
      const int r = pass * 8 + r0;
      const float4 v = *(const float4*)&feat[(size_t)(b0 + r) * NK3 + k0 + ci * 4];
      As[r][ci * 4 + 0] = v.x; As[r][ci * 4 + 1] = v.y;
      As[r][ci * 4 + 2] = v.z; As[r][ci * 4 + 3] = v.w;
    }
  }
  {
    const int ci = t & 15, r0 = t >> 4;
#pragma unroll
    for (int pass = 0; pass < 8; ++pass) {
      const int r = pass * 16 + r0;
      *(float4*)&Ws[r][ci * 4] = *(const float4*)&k3[(size_t)(k0 + r) * NO + o0 + ci * 4];
    }
  }
  __syncthreads();
  const int tx = t & 15, ty = t >> 4;
  float acc[4][4] = {};
#pragma unroll 2
  for (int k = 0; k < 128; ++k) {
    const float4 wv = *(const float4*)&Ws[k][tx * 4];
#pragma unroll
    for (int i = 0; i < 4; ++i) {
      const float av = As[ty * 4 + i][k];
      acc[i][0] = fmaf(av, wv.x, acc[i][0]);
      acc[i][1] = fmaf(av, wv.y, acc[i][1]);
      acc[i][2] = fmaf(av, wv.z, acc[i][2]);
      acc[i][3] = fmaf(av, wv.w, acc[i][3]);
    }
  }
  float* base = pB + ((size_t)blockIdx.z * NB + b0) * NO + o0;
#pragma unroll
  for (int i = 0; i < 4; ++i)
    *(float4*)&base[(ty * 4 + i) * NO + tx * 4] =
        make_float4(acc[i][0], acc[i][1], acc[i][2], acc[i][3]);
}

__global__ __launch_bounds__(256) void combineB_kernel(
    const float* __restrict__ pB, const float* __restrict__ bias3,
    float* __restrict__ out) {
  const int p = blockIdx.x * 256 + threadIdx.x;
  const int b = p >> 9, o = p & 511;
  float s = bias3[o];
#pragma unroll
  for (int ks = 0; ks < 12; ++ks) s += pB[((size_t)ks * NB + b) * NO + o];
  out[p] = s;
}

extern "C" void kernel_launch(void* const* d_in, const int* in_sizes, int n_in,
                              void* d_out, int out_size, void* d_ws, size_t ws_size,
                              hipStream_t stream) {
  const float* x    = (const float*)d_in[0];
  const float* gt   = (const float*)d_in[1];
  const float* wt   = (const float*)d_in[2];
  const float* mt   = (const float*)d_in[3];
  const float* k1   = (const float*)d_in[4];
  const float* b1   = (const float*)d_in[5];
  const float* k3   = (const float*)d_in[6];
  const float* b3   = (const float*)d_in[7];
  const float* embk = (const float*)d_in[8];
  const float* embb = (const float*)d_in[9];
  const float* ekd  = (const float*)d_in[10];
  const float* ng   = (const float*)d_in[11];
  const float* nb   = (const float*)d_in[12];
  float* ws = (float*)d_ws;
  float* Tpart = ws + WS_TPART;
  float* pA = ws + WS_PA;
  float* feat = ws + WS_FEAT;
  float* pB = ws + WS_PB;
  float* out = (float*)d_out;

  hipLaunchKernelGGL(attn_kernel, dim3(4, NB), dim3(256), 0, stream,
                     x, embk, embb, ekd, Tpart);
  hipLaunchKernelGGL(gemmA_kernel, dim3(8, 2, 32), dim3(256), 0, stream,
                     x, gt, wt, mt, k1, pA);
  hipLaunchKernelGGL(combineA_kernel, dim3(256), dim3(256), 0, stream,
                     pA, Tpart, b1, embk, embb, ekd, ng, nb, feat);
  hipLaunchKernelGGL(gemmB_kernel, dim3(8, 2, 12), dim3(256), 0, stream,
                     feat, k3, pB);
  hipLaunchKernelGGL(combineB_kernel, dim3(256), dim3(256), 0, stream,
                     pB, b3, out);
}

// Round 2
// 33.389 us; speedup vs baseline: 2.0921x; 2.0921x over previous
//
#include <hip/hip_runtime.h>
#include <hip/hip_bf16.h>
#include <math.h>

typedef unsigned short u16;
typedef __attribute__((ext_vector_type(8))) short bf16x8;
typedef __attribute__((ext_vector_type(4))) float f32x4;

#define NB 128
#define ND 1024
#define NO 512
#define NK3 1536
#define EPSV 1e-5f
#define SCALEQK 0.04419417382415922f   // 1/sqrt(512)
#define LOG2E 1.4426950408889634f

static __device__ __forceinline__ float fast_exp2(float v) {
#if __has_builtin(__builtin_amdgcn_exp2f)
  return __builtin_amdgcn_exp2f(v);
#else
  return exp2f(v);
#endif
}

static __device__ __forceinline__ u16 bf16_rtn(float f) {
  unsigned u = __float_as_uint(f);
  return (u16)((u + 0x7FFFu + ((u >> 16) & 1u)) >> 16);
}
static __device__ __forceinline__ void bf16_split(float f, u16& h, u16& l) {
  h = bf16_rtn(f);
  l = bf16_rtn(f - __uint_as_float(((unsigned)h) << 16));
}

// =============== K1: attention moments (blocks 0..127) + bf16 prep (128..255) ===============
__global__ __launch_bounds__(256) void k1_attn_prep(
    const float* __restrict__ x, const float* __restrict__ embk,
    const float* __restrict__ embb, const float* __restrict__ ekd,
    float* __restrict__ Tfull, u16* __restrict__ xh, u16* __restrict__ xl,
    u16* __restrict__ ah, u16* __restrict__ al) {
  const int t = threadIdx.x;
  const int bid = blockIdx.x;
  if (bid >= NB) {
    // prep: split x and asinh(x) rows into bf16 hi/lo
    const int r = bid - NB;
    const int base = r * ND + t * 4;
    const float4 v = *(const float4*)&x[base];
    const float vv[4] = {v.x, v.y, v.z, v.w};
    unsigned ph[2], pl[2], pah[2], pal[2];
#pragma unroll
    for (int i = 0; i < 2; ++i) {
      u16 h0, l0, h1, l1, g0, q0, g1, q1;
      bf16_split(vv[2 * i], h0, l0);
      bf16_split(vv[2 * i + 1], h1, l1);
      const float a0 = asinhf(vv[2 * i]);
      const float a1 = asinhf(vv[2 * i + 1]);
      bf16_split(a0, g0, q0);
      bf16_split(a1, g1, q1);
      ph[i] = (unsigned)h0 | ((unsigned)h1 << 16);
      pl[i] = (unsigned)l0 | ((unsigned)l1 << 16);
      pah[i] = (unsigned)g0 | ((unsigned)g1 << 16);
      pal[i] = (unsigned)q0 | ((unsigned)q1 << 16);
    }
    *(uint2*)&xh[base] = make_uint2(ph[0], ph[1]);
    *(uint2*)&xl[base] = make_uint2(pl[0], pl[1]);
    *(uint2*)&ah[base] = make_uint2(pah[0], pah[1]);
    *(uint2*)&al[base] = make_uint2(pal[0], pal[1]);
    return;
  }
  // attention: T_b = sum_d ekd_d * t[b,d]; t via tilted moments + Taylor in delta
  __shared__ float xsh[ND];
  __shared__ float red[11][4];
  __shared__ float bc[13];
  *(float4*)&xsh[t * 4] = *(const float4*)&x[bid * ND + t * 4];
  float s1, s3;
  {
    float qk = embk[t], kk = embk[NO + t], qb = embb[t];
    s1 = qk * kk;
    s3 = kk * qb;
    qk = embk[t + 256]; kk = embk[NO + t + 256]; qb = embb[t + 256];
    s1 = fmaf(qk, kk, s1);
    s3 = fmaf(kk, qb, s3);
  }
#pragma unroll
  for (int off = 32; off; off >>= 1) {
    s1 += __shfl_xor(s1, off);
    s3 += __shfl_xor(s3, off);
  }
  const int w = t >> 6;
  if ((t & 63) == 0) { red[0][w] = s1; red[1][w] = s3; }
  __syncthreads();
  if (t < 2) bc[t] = red[t][0] + red[t][1] + red[t][2] + red[t][3];
  __syncthreads();
  const float S1 = bc[0], S3 = bc[1];
  const float aL2 = SCALEQK * LOG2E * S3;  // exp(a*x) = exp2(aL2*x)
  const float dS1 = SCALEQK * S1;          // delta_d = dS1 * x_bd (natural log domain)
  float mm[11];
#pragma unroll
  for (int k = 0; k < 11; ++k) mm[k] = 0.f;
#pragma unroll
  for (int j = 0; j < 4; ++j) {
    const float xe = xsh[t * 4 + j];
    float p = fast_exp2(aL2 * xe);
    mm[0] += p;
#pragma unroll
    for (int k = 1; k < 11; ++k) { p *= xe; mm[k] += p; }
  }
#pragma unroll
  for (int off = 32; off; off >>= 1)
#pragma unroll
    for (int k = 0; k < 11; ++k) mm[k] += __shfl_xor(mm[k], off);
  if ((t & 63) == 0)
#pragma unroll
    for (int k = 0; k < 11; ++k) red[k][w] = mm[k];
  __syncthreads();
  if (t < 11) bc[2 + t] = red[t][0] + red[t][1] + red[t][2] + red[t][3];
  __syncthreads();
  const float invf[10] = {1.f, 1.f, 0.5f, 1.6666667e-1f, 4.1666668e-2f,
                          8.3333333e-3f, 1.3888889e-3f, 1.9841270e-4f,
                          2.4801587e-5f, 2.7557319e-6f};
  float cn[10], cd[10];
#pragma unroll
  for (int k = 0; k < 10; ++k) {
    cn[k] = bc[3 + k] * invf[k];  // M_{k+1}/k!
    cd[k] = bc[2 + k] * invf[k];  // M_k/k!
  }
  float Ta = 0.f;
#pragma unroll
  for (int j = 0; j < 4; ++j) {
    const int d = t * 4 + j;
    const float del = dS1 * xsh[d];
    float num = cn[9], den = cd[9];
#pragma unroll
    for (int k = 8; k >= 0; --k) {
      num = fmaf(num, del, cn[k]);
      den = fmaf(den, del, cd[k]);
    }
    Ta = fmaf(ekd[d], num / den, Ta);
  }
#pragma unroll
  for (int off = 32; off; off >>= 1) Ta += __shfl_xor(Ta, off);
  __syncthreads();
  if ((t & 63) == 0) red[0][w] = Ta;
  __syncthreads();
  if (t == 0) Tfull[bid] = red[0][0] + red[0][1] + red[0][2] + red[0][3];
}

// =============== shared MFMA GEMM block: 128x64 tile, K-span 128 (2 chunks of 64) ===============
// bf16 hi/lo 3-pass emulated fp32. LDS tiles XOR-swizzled (byte ^= (row&7)<<4).
template <int WMODE>
static __device__ __forceinline__ void gemm_block(
    const u16* __restrict__ Ah, const u16* __restrict__ Al, int lda,
    const float* __restrict__ W0, const float* __restrict__ W1,
    float* __restrict__ outp, int o0, int k0,
    u16* AshH, u16* AshL, u16* BshH, u16* BshL) {
  const int t = threadIdx.x;
  const int lane = t & 63;
  const int w = t >> 6;
  const f32x4 vz = {0.f, 0.f, 0.f, 0.f};
  f32x4 acc[2][4];
#pragma unroll
  for (int m = 0; m < 2; ++m)
#pragma unroll
    for (int n = 0; n < 4; ++n) acc[m][n] = vz;

#pragma unroll
  for (int c = 0; c < 2; ++c) {
    const int kc = k0 + c * 64;
    if (c) __syncthreads();
    // ---- stage A: 128 rows x 64 k (bf16 h/l from global, already split) ----
    {
      const int row = t >> 1, half = t & 1;
      const u16* gh = Ah + (size_t)row * lda + kc + half * 32;
      const u16* gl = Al + (size_t)row * lda + kc + half * 32;
      const int swz = (row & 7) << 4;
#pragma unroll
      for (int jj = 0; jj < 4; ++jj) {
        const uint4 vh = *(const uint4*)(gh + jj * 8);
        const uint4 vl = *(const uint4*)(gl + jj * 8);
        const int byte = (row * 128 + half * 64 + jj * 16) ^ swz;
        *(uint4*)((char*)AshH + byte) = vh;
        *(uint4*)((char*)AshL + byte) = vl;
      }
    }
    // ---- stage B transposed: Wt[col][k], 64 cols x 64 k, fp32 -> bf16 h/l ----
#pragma unroll
    for (int s2 = 0; s2 < 2; ++s2) {
      const int s = t + s2 * 256;
      const int kp = s >> 4, og = s & 15;
      const int gk = kc + kp * 2, go = o0 + og * 4;
      float4 w0 = *(const float4*)&W0[(size_t)gk * NO + go];
      float4 w1 = *(const float4*)&W0[(size_t)(gk + 1) * NO + go];
      if (WMODE) {
        const float4 m0 = *(const float4*)&W1[(size_t)gk * NO + go];
        const float4 m1 = *(const float4*)&W1[(size_t)(gk + 1) * NO + go];
        w0.x = tanhf(w0.x) / (1.f + __expf(-m0.x));
        w0.y = tanhf(w0.y) / (1.f + __expf(-m0.y));
        w0.z = tanhf(w0.z) / (1.f + __expf(-m0.z));
        w0.w = tanhf(w0.w) / (1.f + __expf(-m0.w));
        w1.x = tanhf(w1.x) / (1.f + __expf(-m1.x));
        w1.y = tanhf(w1.y) / (1.f + __expf(-m1.y));
        w1.z = tanhf(w1.z) / (1.f + __expf(-m1.z));
        w1.w = tanhf(w1.w) / (1.f + __expf(-m1.w));
      }
      const float e0[4] = {w0.x, w0.y, w0.z, w0.w};
      const float e1[4] = {w1.x, w1.y, w1.z, w1.w};
#pragma unroll
      for (int j = 0; j < 4; ++j) {
        u16 h0, l0, h1, l1;
        bf16_split(e0[j], h0, l0);
        bf16_split(e1[j], h1, l1);
        const int col = og * 4 + j;
        const int byte = (col * 128 + kp * 4) ^ ((col & 7) << 4);
        *(unsigned*)((char*)BshH + byte) = (unsigned)h0 | ((unsigned)h1 << 16);
        *(unsigned*)((char*)BshL + byte) = (unsigned)l0 | ((unsigned)l1 << 16);
      }
    }
    __syncthreads();
    // ---- compute: 2 k-steps of 32 ----
#pragma unroll
    for (int ks2 = 0; ks2 < 2; ++ks2) {
      const int kb = ((lane >> 4) * 16) + ks2 * 64;
      bf16x8 a_h[2], a_l[2], b_h[4], b_l[4];
#pragma unroll
      for (int m = 0; m < 2; ++m) {
        const int row = w * 32 + m * 16 + (lane & 15);
        const int byte = (row * 128 + kb) ^ ((row & 7) << 4);
        a_h[m] = *(const bf16x8*)((const char*)AshH + byte);
        a_l[m] = *(const bf16x8*)((const char*)AshL + byte);
      }
#pragma unroll
      for (int n = 0; n < 4; ++n) {
        const int col = n * 16 + (lane & 15);
        const int byte = (col * 128 + kb) ^ ((col & 7) << 4);
        b_h[n] = *(const bf16x8*)((const char*)BshH + byte);
        b_l[n] = *(const bf16x8*)((const char*)BshL + byte);
      }
#pragma unroll
      for (int m = 0; m < 2; ++m)
#pragma unroll
        for (int n = 0; n < 4; ++n) {
          acc[m][n] = __builtin_amdgcn_mfma_f32_16x16x32_bf16(a_h[m], b_h[n], acc[m][n], 0, 0, 0);
          acc[m][n] = __builtin_amdgcn_mfma_f32_16x16x32_bf16(a_h[m], b_l[n], acc[m][n], 0, 0, 0);
          acc[m][n] = __builtin_amdgcn_mfma_f32_16x16x32_bf16(a_l[m], b_h[n], acc[m][n], 0, 0, 0);
        }
    }
  }
  // ---- epilogue: C/D layout col=lane&15, row=(lane>>4)*4+reg ----
#pragma unroll
  for (int m = 0; m < 2; ++m)
#pragma unroll
    for (int n = 0; n < 4; ++n)
#pragma unroll
      for (int r = 0; r < 4; ++r) {
        const int row = w * 32 + m * 16 + (lane >> 4) * 4 + r;
        const int col = o0 + n * 16 + (lane & 15);
        outp[(size_t)row * NO + col] = acc[m][n][r];
      }
}

// =============== gemmA: 4 GEMMs (x@k1, x@gt, x@wa, asinh(x)@wa), ksplit 8 ===============
__global__ __launch_bounds__(256) void gemmA_mfma(
    const u16* __restrict__ xh, const u16* __restrict__ xl,
    const u16* __restrict__ ash, const u16* __restrict__ asl,
    const float* __restrict__ gt, const float* __restrict__ wt,
    const float* __restrict__ mt, const float* __restrict__ k1,
    float* __restrict__ pA) {
  __shared__ __align__(16) u16 AshH[128 * 64];
  __shared__ __align__(16) u16 AshL[128 * 64];
  __shared__ __align__(16) u16 BshH[64 * 64];
  __shared__ __align__(16) u16 BshL[64 * 64];
  const int bx = blockIdx.x;
  const int o0 = (bx & 7) * 64;
  const int ks = (bx >> 3) & 7;
  const int g = bx >> 6;
  const int k0 = ks * 128;
  float* outp = pA + (size_t)(g * 8 + ks) * (NB * NO);
  if (g == 0)
    gemm_block<0>(xh, xl, ND, k1, k1, outp, o0, k0, AshH, AshL, BshH, BshL);
  else if (g == 1)
    gemm_block<0>(xh, xl, ND, gt, gt, outp, o0, k0, AshH, AshL, BshH, BshL);
  else if (g == 2)
    gemm_block<1>(xh, xl, ND, wt, mt, outp, o0, k0, AshH, AshL, BshH, BshL);
  else
    gemm_block<1>(ash, asl, ND, wt, mt, outp, o0, k0, AshH, AshL, BshH, BshL);
}

// =============== combineA: nonlinearities + c4 layernorm -> feat (bf16 h/l) ===============
__global__ __launch_bounds__(256) void combineA_kernel(
    const float* __restrict__ pA, const float* __restrict__ Tfull,
    const float* __restrict__ bias1, const float* __restrict__ embk,
    const float* __restrict__ embb, const float* __restrict__ ekd,
    const float* __restrict__ ng, const float* __restrict__ nbv,
    u16* __restrict__ featH, u16* __restrict__ featL) {
  __shared__ float red[6][4];
  __shared__ float bc[6];
  const int t = threadIdx.x;
  const int p = blockIdx.x * 256 + t;
  const int b = p >> 9, o = p & 511;

  float svk = 0, svb = 0, svk2 = 0, svkvb = 0, svb2 = 0, se = 0;
#pragma unroll
  for (int j = 0; j < 2; ++j) {
    const int oo = t + j * 256;
    const float vk = embk[2 * NO + oo], vb = embb[2 * NO + oo];
    svk += vk; svb += vb;
    svk2 = fmaf(vk, vk, svk2);
    svkvb = fmaf(vk, vb, svkvb);
    svb2 = fmaf(vb, vb, svb2);
  }
#pragma unroll
  for (int j = 0; j < 4; ++j) se += ekd[t + j * 256];
#pragma unroll
  for (int off = 32; off; off >>= 1) {
    svk += __shfl_xor(svk, off); svb += __shfl_xor(svb, off);
    svk2 += __shfl_xor(svk2, off); svkvb += __shfl_xor(svkvb, off);
    svb2 += __shfl_xor(svb2, off); se += __shfl_xor(se, off);
  }
  const int w = t >> 6;
  if ((t & 63) == 0) {
    red[0][w] = svk; red[1][w] = svb; red[2][w] = svk2;
    red[3][w] = svkvb; red[4][w] = svb2; red[5][w] = se;
  }
  __syncthreads();
  if (t < 6) bc[t] = red[t][0] + red[t][1] + red[t][2] + red[t][3];
  __syncthreads();
  const float inv_o = 1.f / (float)NO;
  const float mvk = bc[0] * inv_o, mvb = bc[1] * inv_o;
  const float Mvk2 = bc[2] * inv_o - mvk * mvk;
  const float Mvkvb = bc[3] * inv_o - mvk * mvb;
  const float Mvb2 = bc[4] * inv_o - mvb * mvb;
  const float E = bc[5];

  float d1 = 0, d2 = 0, d3 = 0, d4 = 0;
#pragma unroll
  for (int ks = 0; ks < 8; ++ks) {
    d1 += pA[((size_t)(0 * 8 + ks) * NB + b) * NO + o];
    d2 += pA[((size_t)(1 * 8 + ks) * NB + b) * NO + o];
    d3 += pA[((size_t)(2 * 8 + ks) * NB + b) * NO + o];
    d4 += pA[((size_t)(3 * 8 + ks) * NB + b) * NO + o];
  }
  const float c1v = d1 + bias1[o];
  const float gg = 1.f / (1.f + __expf(-d2));
  const float mmv = sinhf(d4);
  const float c3v = fmaf(gg, d3 - mmv, mmv);
  const float T = Tfull[b];
  const float vkc = embk[2 * NO + o] - mvk, vbc = embb[2 * NO + o] - mvb;
  const float var = T * T * Mvk2 + 2.f * T * E * Mvkvb + E * E * Mvb2;
  const float c4v = (T * vkc + E * vbc) * rsqrtf(var + EPSV) * ng[o] + nbv[o];

  u16* fH = featH + (size_t)b * NK3;
  u16* fL = featL + (size_t)b * NK3;
  u16 h, l;
  bf16_split(c1v, h, l); fH[o] = h; fL[o] = l;
  bf16_split(c3v, h, l); fH[NO + o] = h; fL[NO + o] = l;
  bf16_split(c4v, h, l); fH[2 * NO + o] = h; fL[2 * NO + o] = l;
}

// =============== gemmB: feat[128,1536] @ k3[1536,512], ksplit 12 ===============
__global__ __launch_bounds__(256) void gemmB_mfma(
    const u16* __restrict__ fh, const u16* __restrict__ fl,
    const float* __restrict__ k3, float* __restrict__ pB) {
  __shared__ __align__(16) u16 AshH[128 * 64];
  __shared__ __align__(16) u16 AshL[128 * 64];
  __shared__ __align__(16) u16 BshH[64 * 64];
  __shared__ __align__(16) u16 BshL[64 * 64];
  const int bx = blockIdx.x;
  const int o0 = (bx & 7) * 64;
  const int ks = bx >> 3;
  gemm_block<0>(fh, fl, NK3, k3, k3, pB + (size_t)ks * (NB * NO), o0, ks * 128,
                AshH, AshL, BshH, BshL);
}

__global__ __launch_bounds__(256) void combineB_kernel(
    const float* __restrict__ pB, const float* __restrict__ bias3,
    float* __restrict__ out) {
  const int p = blockIdx.x * 256 + threadIdx.x;
  const int b = p >> 9, o = p & 511;
  float s = bias3[o];
#pragma unroll
  for (int ks = 0; ks < 12; ++ks) s += pB[((size_t)ks * NB + b) * NO + o];
  out[p] = s;
}

extern "C" void kernel_launch(void* const* d_in, const int* in_sizes, int n_in,
                              void* d_out, int out_size, void* d_ws, size_t ws_size,
                              hipStream_t stream) {
  const float* x    = (const float*)d_in[0];
  const float* gt   = (const float*)d_in[1];
  const float* wt   = (const float*)d_in[2];
  const float* mt   = (const float*)d_in[3];
  const float* k1   = (const float*)d_in[4];
  const float* b1   = (const float*)d_in[5];
  const float* k3   = (const float*)d_in[6];
  const float* b3   = (const float*)d_in[7];
  const float* embk = (const float*)d_in[8];
  const float* embb = (const float*)d_in[9];
  const float* ekd  = (const float*)d_in[10];
  const float* ng   = (const float*)d_in[11];
  const float* nb   = (const float*)d_in[12];

  char* wsb = (char*)d_ws;
  float* Tfull = (float*)wsb;                               // 512 B
  u16* xh  = (u16*)(wsb + (1u << 20));                      // 256 KB each
  u16* xl  = (u16*)(wsb + (1u << 20) + (256u << 10));
  u16* ahp = (u16*)(wsb + (1u << 20) + (512u << 10));
  u16* alp = (u16*)(wsb + (1u << 20) + (768u << 10));
  float* pA = (float*)(wsb + (2u << 20));                   // 8 MB
  u16* featH = (u16*)(wsb + (10u << 20));                   // 384 KB
  u16* featL = (u16*)(wsb + (10u << 20) + (512u << 10));    // 384 KB
  float* pB = (float*)(wsb + (11u << 20));                  // 3 MB
  float* out = (float*)d_out;

  hipLaunchKernelGGL(k1_attn_prep, dim3(256), dim3(256), 0, stream,
                     x, embk, embb, ekd, Tfull, xh, xl, ahp, alp);
  hipLaunchKernelGGL(gemmA_mfma, dim3(256), dim3(256), 0, stream,
                     xh, xl, ahp, alp, gt, wt, mt, k1, pA);
  hipLaunchKernelGGL(combineA_kernel, dim3(256), dim3(256), 0, stream,
                     pA, Tfull, b1, embk, embb, ekd, ng, nb, featH, featL);
  hipLaunchKernelGGL(gemmB_mfma, dim3(96), dim3(256), 0, stream,
                     featH, featL, k3, pB);
  hipLaunchKernelGGL(combineB_kernel, dim3(256), dim3(256), 0, stream,
                     pB, b3, out);
}